// Round 4
// baseline (183.987 us; speedup 1.0000x reference)
//
#include <hip/hip_runtime.h>
#include <math.h>

#define S_LEN 2048
#define NH    16
#define DD    128
#define SROW  (NH*DD)      // 2048 elems between consecutive s
#define WIN2  512          // merged window (two streams union)
#define BQ    128          // queries per workgroup
#define BK    64           // keys per chunk
#define RSQ   136          // LDS stride for d-major rows (128 elems + 8 pad)
#define RS    72           // LDS stride for key-major rows (64 elems + 8 pad)

typedef __bf16 bf16x8 __attribute__((ext_vector_type(8)));
typedef __bf16 bf16x4 __attribute__((ext_vector_type(4)));
typedef float  f32x4  __attribute__((ext_vector_type(4)));

__device__ __forceinline__ f32x4 mfma16(bf16x8 a, bf16x8 b, f32x4 c) {
    return __builtin_amdgcn_mfma_f32_16x16x32_bf16(a, b, c, 0, 0, 0);
}

__device__ __forceinline__ unsigned int pack_bf16(float lo, float hi) {
    return (unsigned int)__builtin_bit_cast(unsigned short, (__bf16)lo)
         | ((unsigned int)__builtin_bit_cast(unsigned short, (__bf16)hi) << 16);
}

// Shared layout (bf16 elems):
//   [0,            8704)  : sK   64 rows x RSQ   ([key][d])
//   [8704,        17920)  : sVt 128 rows x RS    ([d][key])
//   [17920,       27136)  : sP  4 waves x 32 x RS ([q][key])
// Q staging transiently overlays [0, 17408) (128 rows x RSQ) pre-loop.
#define OFF_VT 8704
#define OFF_P  17920
#define SMEM_ELEMS 27136

__global__ __launch_bounds__(256, 2)
void swattn_kernel(const float* __restrict__ Qg, const float* __restrict__ Kg,
                   const float* __restrict__ Vg, float* __restrict__ Og) {
    __shared__ __align__(16) __bf16 smem[SMEM_ELEMS];

    const int t   = threadIdx.x;
    const int w   = t >> 6;        // wave 0..3
    const int l   = t & 63;        // lane
    const int r16 = l & 15;
    const int g4  = l >> 4;        // quarter-wave 0..3
    const int qt  = blockIdx.x;
    const int h   = blockIdx.y;
    const int b   = blockIdx.z;
    const int Qlo = qt * BQ;

    const size_t bh = ((size_t)b * S_LEN) * SROW + (size_t)h * DD;

    // K staging map: thread t, iter it -> row it*8+(t>>5), col 4*(t&31)
    const int kst_row = t >> 5;
    const int kst_col = (t & 31) * 4;
    // V staging map: wave handles 16 keys, pair per iter; gv = key of pair,
    // rv = d-quad (float4 covers d=4rv..4rv+3)
    const int gv = l >> 5;
    const int rv = l & 31;

    float4 kpre[8], vpre[8];   // prefetch registers (next chunk)

    auto issue_loads = [&](int c0) {
#pragma unroll
        for (int it = 0; it < 8; ++it)
            kpre[it] = *(const float4*)&Kg[bh + (size_t)(c0 + it*8 + kst_row) * SROW + kst_col];
#pragma unroll
        for (int it = 0; it < 8; ++it) {
            int k0l = w * 16 + it * 2;
            vpre[it] = *(const float4*)&Vg[bh + (size_t)(c0 + k0l + gv) * SROW + 4*rv];
        }
    };

    auto write_stage = [&]() {
        // K chunk -> [key][d] bf16, stride RSQ
#pragma unroll
        for (int it = 0; it < 8; ++it) {
            const float4 v = kpre[it];
            bf16x4 o4 = { (__bf16)v.x, (__bf16)v.y, (__bf16)v.z, (__bf16)v.w };
            *(bf16x4*)&smem[(it*8 + kst_row) * RSQ + kst_col] = o4;
        }
        // V chunk -> V^T[d][key] bf16, stride RS (pair-exchange shfl_xor(32);
        // gv=0 writes d-rows 4rv,4rv+1; gv=1 writes 4rv+2,4rv+3; 2-key b32 each)
#pragma unroll
        for (int it = 0; it < 8; ++it) {
            int k0l = w * 16 + it * 2;
            const float4 v4 = vpre[it];
            float ox = __shfl_xor(v4.x, 32);
            float oy = __shfl_xor(v4.y, 32);
            float oz = __shfl_xor(v4.z, 32);
            float ow = __shfl_xor(v4.w, 32);
            float lo0, hi0, lo1, hi1; int d0;
            if (gv == 0) { lo0 = v4.x; hi0 = ox;   lo1 = v4.y; hi1 = oy;   d0 = 4*rv; }
            else         { lo0 = oz;   hi0 = v4.z; lo1 = ow;   hi1 = v4.w; d0 = 4*rv + 2; }
            *(unsigned int*)&smem[OFF_VT + (d0    ) * RS + k0l] = pack_bf16(lo0, hi0);
            *(unsigned int*)&smem[OFF_VT + (d0 + 1) * RS + k0l] = pack_bf16(lo1, hi1);
        }
    };

    int cb = Qlo - (WIN2 - 1);
    if (cb < 0) cb = 0;
    cb &= ~(BK - 1);
    const int Qhi = Qlo + BQ - 1;

    // ---------- prefetch chunk 0 (oldest in queue), then stage Q ----------
    issue_loads(cb);

    for (int it = 0; it < 16; ++it) {
        int f   = it * 256 + t;
        int q_l = f >> 5;          // 0..127
        int dq  = (f & 31) * 4;    // 0..124
        const float4 v = *(const float4*)&Qg[bh + (size_t)(Qlo + q_l) * SROW + dq];
        bf16x4 o4 = { (__bf16)v.x, (__bf16)v.y, (__bf16)v.z, (__bf16)v.w };
        *(bf16x4*)&smem[q_l * RSQ + dq] = o4;
    }
    __syncthreads();

    bf16x8 qf[2][4];   // [qgroup][dslice] : B-operand, n=q=lane&15, k=d
#pragma unroll
    for (int qg = 0; qg < 2; ++qg)
#pragma unroll
        for (int sl = 0; sl < 4; ++sl)
            qf[qg][sl] = *(const bf16x8*)&smem[(w*32 + qg*16 + r16) * RSQ + sl*32 + g4*8];
    __syncthreads();

    const f32x4 zero4 = {0.f, 0.f, 0.f, 0.f};
    f32x4 oacc[8][2];  // O^T frags: [dgroup][qgroup]; lane: d=dg*16+4*g4+reg, q=qg*16+r16
#pragma unroll
    for (int dg = 0; dg < 8; ++dg) { oacc[dg][0] = zero4; oacc[dg][1] = zero4; }
    float m_run[2] = { -1e30f, -1e30f };
    float l_run[2] = { 0.f, 0.f };

    const int q_lo_w = Qlo + w * 32;
    const int q_hi_w = q_lo_w + 31;
    const float C1 = 0.08838834764831845f * 1.44269504088896340f;  // scale * log2(e)

    for (int c0 = cb; c0 <= Qhi; c0 += BK) {
        // ---- regs (chunk c) -> LDS ----
        write_stage();
        __syncthreads();   // barrier1: staged tile visible

        // ---- prefetch chunk c+1 (hides HBM latency behind compute) ----
        if (c0 + BK <= Qhi) issue_loads(c0 + BK);

        const bool act = (q_hi_w >= c0) && (q_lo_w <= c0 + (BK - 1) + (WIN2 - 1));
        if (act) {
            // ---- S^T = K · Q^T : C-layout lane: key=kg*16+4*g4+reg, q=qg*16+r16 ----
            f32x4 st[4][2];
#pragma unroll
            for (int kg = 0; kg < 4; ++kg) { st[kg][0] = zero4; st[kg][1] = zero4; }
#pragma unroll
            for (int sl = 0; sl < 4; ++sl)
#pragma unroll
                for (int kg = 0; kg < 4; ++kg) {
                    bf16x8 kf = *(const bf16x8*)&smem[(kg*16 + r16) * RSQ + sl*32 + g4*8];
                    st[kg][0] = mfma16(kf, qf[0][sl], st[kg][0]);
                    st[kg][1] = mfma16(kf, qf[1][sl], st[kg][1]);
                }

            // ---- mask + scale (log2 domain) ----
            const bool fv = (q_lo_w >= c0 + (BK - 1)) && (q_hi_w <= c0 + (WIN2 - 1));
            if (fv) {
#pragma unroll
                for (int kg = 0; kg < 4; ++kg)
#pragma unroll
                    for (int qg = 0; qg < 2; ++qg)
#pragma unroll
                        for (int rg = 0; rg < 4; ++rg) st[kg][qg][rg] *= C1;
            } else {
#pragma unroll
                for (int qg = 0; qg < 2; ++qg) {
                    int iq = q_lo_w + qg*16 + r16;
#pragma unroll
                    for (int kg = 0; kg < 4; ++kg) {
                        int relb = iq - (c0 + kg*16 + 4*g4);
#pragma unroll
                        for (int rg = 0; rg < 4; ++rg) {
                            bool ok = ((unsigned)(relb - rg)) < (unsigned)WIN2;
                            st[kg][qg][rg] = ok ? st[kg][qg][rg] * C1 : -1e30f;
                        }
                    }
                }
            }

            // ---- online softmax per q-column (in-lane over 16 keys; 2 shfls) ----
            float alpha[2];
#pragma unroll
            for (int qg = 0; qg < 2; ++qg) {
                float mc = -1e30f;
#pragma unroll
                for (int kg = 0; kg < 4; ++kg)
#pragma unroll
                    for (int rg = 0; rg < 4; ++rg) mc = fmaxf(mc, st[kg][qg][rg]);
                mc = fmaxf(mc, __shfl_xor(mc, 16));
                mc = fmaxf(mc, __shfl_xor(mc, 32));
                float mn = fmaxf(m_run[qg], mc);
                alpha[qg] = exp2f(m_run[qg] - mn);
                m_run[qg] = mn;
                float sum = 0.f;
#pragma unroll
                for (int kg = 0; kg < 4; ++kg)
#pragma unroll
                    for (int rg = 0; rg < 4; ++rg) {
                        float tv = st[kg][qg][rg];
                        float p  = exp2f(tv - mn);
                        if (!fv) p = (tv > -1e29f) ? p : 0.f;  // all-masked guard
                        st[kg][qg][rg] = p;
                        sum += p;
                    }
                sum += __shfl_xor(sum, 16);
                sum += __shfl_xor(sum, 32);
                l_run[qg] = l_run[qg] * alpha[qg] + sum;
            }

            // ---- P -> LDS as [q][key] bf16: lane's 4 regs = 4 consecutive keys ----
#pragma unroll
            for (int qg = 0; qg < 2; ++qg)
#pragma unroll
                for (int kg = 0; kg < 4; ++kg) {
                    f32x4 pv = st[kg][qg];
                    bf16x4 p4 = { (__bf16)pv[0], (__bf16)pv[1], (__bf16)pv[2], (__bf16)pv[3] };
                    *(bf16x4*)&smem[OFF_P + (w*32 + qg*16 + r16) * RS + kg*16 + 4*g4] = p4;
                }

            // ---- rescale O ----
#pragma unroll
            for (int dg = 0; dg < 8; ++dg)
#pragma unroll
                for (int qg = 0; qg < 2; ++qg)
#pragma unroll
                    for (int rg = 0; rg < 4; ++rg) oacc[dg][qg][rg] *= alpha[qg];

            // ---- O^T += V^T · P^T : A=V^T frag (m=d), B=P frag (n=q) ----
#pragma unroll
            for (int ks = 0; ks < 2; ++ks) {
                bf16x8 pf0 = *(const bf16x8*)&smem[OFF_P + (w*32 +  0 + r16) * RS + ks*32 + g4*8];
                bf16x8 pf1 = *(const bf16x8*)&smem[OFF_P + (w*32 + 16 + r16) * RS + ks*32 + g4*8];
#pragma unroll
                for (int dg = 0; dg < 8; ++dg) {
                    bf16x8 vf = *(const bf16x8*)&smem[OFF_VT + (dg*16 + r16) * RS + ks*32 + g4*8];
                    oacc[dg][0] = mfma16(vf, pf0, oacc[dg][0]);
                    oacc[dg][1] = mfma16(vf, pf1, oacc[dg][1]);
                }
            }
        }
        __syncthreads();   // barrier2: compute(c) done before staging c+1 (drains vmcnt, latency already hidden)
    }

    // ---------- epilogue: normalize and store (float4 along d, 64B sectors) ----------
    float inv0 = 1.f / l_run[0];
    float inv1 = 1.f / l_run[1];
#pragma unroll
    for (int qg = 0; qg < 2; ++qg) {
        float iv = qg ? inv1 : inv0;
        int q = q_lo_w + qg*16 + r16;
        size_t base = bh + (size_t)q * SROW;
#pragma unroll
        for (int dg = 0; dg < 8; ++dg) {
            f32x4 o = oacc[dg][qg];
            float4 res = { o[0]*iv, o[1]*iv, o[2]*iv, o[3]*iv };
            *(float4*)&Og[base + dg*16 + 4*g4] = res;
        }
    }
}

extern "C" void kernel_launch(void* const* d_in, const int* in_sizes, int n_in,
                              void* d_out, int out_size, void* d_ws, size_t ws_size,
                              hipStream_t stream) {
    const float* q = (const float*)d_in[0];
    const float* k = (const float*)d_in[1];
    const float* v = (const float*)d_in[2];
    float* o = (float*)d_out;
    int B = in_sizes[0] / (S_LEN * NH * DD);
    dim3 grid(S_LEN / BQ, NH, B);
    swattn_kernel<<<grid, 256, 0, stream>>>(q, k, v, o);
}

// Round 5
// 174.834 us; speedup vs baseline: 1.0524x; 1.0524x over previous
//
#include <hip/hip_runtime.h>
#include <math.h>

#define S_LEN 2048
#define NH    16
#define DD    128
#define SROW  (NH*DD)      // 2048 elems between consecutive s
#define WIN2  512          // merged window (two streams union)
#define BQ    128          // queries per workgroup (8 waves x 16 q)
#define BK    64           // keys per chunk
#define RSQ   136          // LDS stride for d-major rows (128 elems + 8 pad)
#define RS    72           // LDS stride for key-major rows (64 elems + 8 pad)

typedef __bf16 bf16x8 __attribute__((ext_vector_type(8)));
typedef __bf16 bf16x4 __attribute__((ext_vector_type(4)));
typedef float  f32x4  __attribute__((ext_vector_type(4)));

__device__ __forceinline__ f32x4 mfma16(bf16x8 a, bf16x8 b, f32x4 c) {
    return __builtin_amdgcn_mfma_f32_16x16x32_bf16(a, b, c, 0, 0, 0);
}

__device__ __forceinline__ unsigned int pack_bf16(float lo, float hi) {
    return (unsigned int)__builtin_bit_cast(unsigned short, (__bf16)lo)
         | ((unsigned int)__builtin_bit_cast(unsigned short, (__bf16)hi) << 16);
}

// Shared layout (bf16 elems):
//   [0,      8704) : sK   64 rows x RSQ  ([key][d])
//   [8704,  17920) : sVt 128 rows x RS   ([d][key], column-swizzled)
//   [17920, 27136) : sP   8 waves x 16 x RS ([q][key])
// Q staging transiently overlays [0, 17408) (128 rows x RSQ) pre-loop.
#define OFF_VT 8704
#define OFF_P  17920
#define SMEM_ELEMS 27136

__global__ __launch_bounds__(512, 4)
void swattn_kernel(const float* __restrict__ Qg, const float* __restrict__ Kg,
                   const float* __restrict__ Vg, float* __restrict__ Og) {
    __shared__ __align__(16) __bf16 smem[SMEM_ELEMS];

    const int t   = threadIdx.x;
    const int w   = t >> 6;        // wave 0..7
    const int l   = t & 63;        // lane
    const int r16 = l & 15;
    const int g4  = l >> 4;        // quarter-wave 0..3
    const int Qlo = blockIdx.x * BQ;
    const int h   = blockIdx.y;
    const int b   = blockIdx.z;

    const size_t bh = ((size_t)b * S_LEN) * SROW + (size_t)h * DD;
    const float C1 = 0.08838834764831845f * 1.44269504088896340f;  // scale * log2(e)

    // ---------- stage Q tile -> LDS bf16, C1 pre-folded ----------
    for (int it = 0; it < 8; ++it) {
        int f   = it * 512 + t;
        int q_l = f >> 5;          // 0..127
        int dq  = (f & 31) * 4;
        const float4 v = *(const float4*)&Qg[bh + (size_t)(Qlo + q_l) * SROW + dq];
        bf16x4 o4 = { (__bf16)(v.x * C1), (__bf16)(v.y * C1),
                      (__bf16)(v.z * C1), (__bf16)(v.w * C1) };
        *(bf16x4*)&smem[q_l * RSQ + dq] = o4;
    }
    __syncthreads();

    bf16x8 qf[4];   // B-operand frags, n=q=lane&15, k=d (wave owns 16 q)
#pragma unroll
    for (int sl = 0; sl < 4; ++sl)
        qf[sl] = *(const bf16x8*)&smem[(w*16 + r16) * RSQ + sl*32 + g4*8];
    __syncthreads();

    const f32x4 zero4 = {0.f, 0.f, 0.f, 0.f};
    f32x4 oacc[8];   // O^T frags: lane holds d=dg*16+4*g4+reg, q=r16
#pragma unroll
    for (int dg = 0; dg < 8; ++dg) oacc[dg] = zero4;
    float m_run = -1e4f;   // finite init: masked exp2 underflows to exact 0, no guard needed
    float l_run = 0.f;

    const int q_w = Qlo + w * 16;   // wave's first query
    const int gv = l >> 5;          // V-staging: which key of the pair
    const int rv = l & 31;          // V-staging: d-quad index

    int cb = Qlo - (WIN2 - 1);
    if (cb < 0) cb = 0;
    cb &= ~(BK - 1);
    const int Qhi = Qlo + BQ - 1;

    for (int c0 = cb; c0 <= Qhi; c0 += BK) {
        // ---- stage K chunk (natural [key][d], stride RSQ) ----
        for (int it = 0; it < 4; ++it) {
            int f   = it * 512 + t;
            int k_l = f >> 5;
            int dq  = (f & 31) * 4;
            const float4 v = *(const float4*)&Kg[bh + (size_t)(c0 + k_l) * SROW + dq];
            bf16x4 o4 = { (__bf16)v.x, (__bf16)v.y, (__bf16)v.z, (__bf16)v.w };
            *(bf16x4*)&smem[k_l * RSQ + dq] = o4;
        }
        // ---- stage V chunk transposed+swizzled: V^T[d][key ^ ((d>>2)&7)<<3] ----
        // Wave handles 8 keys (pair per iter); pair-exchange via shfl_xor(32);
        // gv=0 writes d-rows 4rv,4rv+1; gv=1 writes 4rv+2,4rv+3 (2-key b32 each).
        // Swizzle spreads the write banks (16-way -> 8-way); reads stay even.
        for (int it = 0; it < 4; ++it) {
            int k0l = w * 8 + it * 2;
            const float4 v4 = *(const float4*)&Vg[bh + (size_t)(c0 + k0l + gv) * SROW + 4*rv];
            float ox = __shfl_xor(v4.x, 32);
            float oy = __shfl_xor(v4.y, 32);
            float oz = __shfl_xor(v4.z, 32);
            float ow = __shfl_xor(v4.w, 32);
            float lo0, hi0, lo1, hi1; int d0;
            if (gv == 0) { lo0 = v4.x; hi0 = ox;   lo1 = v4.y; hi1 = oy;   d0 = 4*rv; }
            else         { lo0 = oz;   hi0 = v4.z; lo1 = ow;   hi1 = v4.w; d0 = 4*rv + 2; }
            int col = k0l ^ ((rv & 7) << 3);   // (d0>>2)&7 == rv for both rows
            *(unsigned int*)&smem[OFF_VT + (d0    ) * RS + col] = pack_bf16(lo0, hi0);
            *(unsigned int*)&smem[OFF_VT + (d0 + 1) * RS + col] = pack_bf16(lo1, hi1);
        }
        __syncthreads();

        const bool act = (q_w + 15 >= c0) && (q_w <= c0 + (BK - 1) + (WIN2 - 1));
        if (act) {
            // ---- S^T = K · Q^T : C-layout lane: key=kg*16+4*g4+reg, q=r16 ----
            f32x4 st[4] = { zero4, zero4, zero4, zero4 };
#pragma unroll
            for (int sl = 0; sl < 4; ++sl)
#pragma unroll
                for (int kg = 0; kg < 4; ++kg) {
                    bf16x8 kf = *(const bf16x8*)&smem[(kg*16 + r16) * RSQ + sl*32 + g4*8];
                    st[kg] = mfma16(kf, qf[sl], st[kg]);
                }

            // ---- mask (C1 already folded into Q) ----
            const bool fv = (q_w >= c0 + (BK - 1)) && (q_w + 15 <= c0 + (WIN2 - 1));
            if (!fv) {
                int iq = q_w + r16;
#pragma unroll
                for (int kg = 0; kg < 4; ++kg) {
                    int relb = iq - (c0 + kg*16 + 4*g4);
#pragma unroll
                    for (int rg = 0; rg < 4; ++rg) {
                        bool ok = ((unsigned)(relb - rg)) < (unsigned)WIN2;
                        st[kg][rg] = ok ? st[kg][rg] : -1e30f;
                    }
                }
            }

            // ---- online softmax (in-lane over 16 keys; 2 shfls per stat) ----
            float mc = -1e30f;
#pragma unroll
            for (int kg = 0; kg < 4; ++kg)
#pragma unroll
                for (int rg = 0; rg < 4; ++rg) mc = fmaxf(mc, st[kg][rg]);
            mc = fmaxf(mc, __shfl_xor(mc, 16));
            mc = fmaxf(mc, __shfl_xor(mc, 32));
            float mn = fmaxf(m_run, mc);
            float alpha = exp2f(m_run - mn);
            m_run = mn;
            float sum = 0.f;
#pragma unroll
            for (int kg = 0; kg < 4; ++kg)
#pragma unroll
                for (int rg = 0; rg < 4; ++rg) {
                    float p = exp2f(st[kg][rg] - mn);   // masked -> exact 0 (mn >= -1e4)
                    st[kg][rg] = p;
                    sum += p;
                }
            sum += __shfl_xor(sum, 16);
            sum += __shfl_xor(sum, 32);
            l_run = l_run * alpha + sum;

            // ---- P -> sP [q][key] bf16 (lane's 4 regs = 4 consecutive keys) ----
#pragma unroll
            for (int kg = 0; kg < 4; ++kg) {
                f32x4 pv = st[kg];
                bf16x4 p4 = { (__bf16)pv[0], (__bf16)pv[1], (__bf16)pv[2], (__bf16)pv[3] };
                *(bf16x4*)&smem[OFF_P + (w*16 + r16) * RS + kg*16 + 4*g4] = p4;
            }

            // ---- rescale O ----
#pragma unroll
            for (int dg = 0; dg < 8; ++dg)
#pragma unroll
                for (int rg = 0; rg < 4; ++rg) oacc[dg][rg] *= alpha;

            // ---- O^T += V^T · P^T : A=V^T frag (m=d), B=P frag (n=q) ----
#pragma unroll
            for (int ks = 0; ks < 2; ++ks) {
                bf16x8 pf = *(const bf16x8*)&smem[OFF_P + (w*16 + r16) * RS + ks*32 + g4*8];
#pragma unroll
                for (int dg = 0; dg < 8; ++dg) {
                    // un-swizzle: ((dg*16+r16)>>2)&7 == 4*(dg&1) + (r16>>2)
                    int col = (ks*32 + g4*8) ^ (32*(dg&1) + 8*(r16>>2));
                    bf16x8 vf = *(const bf16x8*)&smem[OFF_VT + (dg*16 + r16) * RS + col];
                    oacc[dg] = mfma16(vf, pf, oacc[dg]);
                }
            }
        }
        __syncthreads();
    }

    // ---------- epilogue: normalize and store (float4 along d) ----------
    float inv = 1.f / l_run;
    int q = q_w + r16;
    size_t base = bh + (size_t)q * SROW;
#pragma unroll
    for (int dg = 0; dg < 8; ++dg) {
        f32x4 o = oacc[dg];
        float4 res = { o[0]*inv, o[1]*inv, o[2]*inv, o[3]*inv };
        *(float4*)&Og[base + dg*16 + 4*g4] = res;
    }
}

extern "C" void kernel_launch(void* const* d_in, const int* in_sizes, int n_in,
                              void* d_out, int out_size, void* d_ws, size_t ws_size,
                              hipStream_t stream) {
    const float* q = (const float*)d_in[0];
    const float* k = (const float*)d_in[1];
    const float* v = (const float*)d_in[2];
    float* o = (float*)d_out;
    int B = in_sizes[0] / (S_LEN * NH * DD);
    dim3 grid(S_LEN / BQ, NH, B);
    swattn_kernel<<<grid, 512, 0, stream>>>(q, k, v, o);
}